// Round 2
// baseline (102.255 us; speedup 1.0000x reference)
//
#include <hip/hip_runtime.h>
#include <hip/hip_bf16.h>

typedef __attribute__((ext_vector_type(4))) float f32x4;
typedef __attribute__((ext_vector_type(8))) short s16x8;
typedef __attribute__((ext_vector_type(4))) unsigned short u16x4;

__device__ __forceinline__ unsigned short f2bf(float f) {
  unsigned u = __builtin_bit_cast(unsigned, f);
  u += 0x7fffu + ((u >> 16) & 1u);
  return (unsigned short)(u >> 16);
}

// ---------------------------------------------------------------------------
// K1: mod[b][j] = silu(emb[b]) . ada_w[j] + ada_b[j]     (32 x 512), pure f32.
// grid(32): block handles 16 j's x all 32 b. 512 threads.
// ---------------------------------------------------------------------------
__global__ __launch_bounds__(512) void k_mod(const float* __restrict__ emb,
                                             const float* __restrict__ ada_w,
                                             const float* __restrict__ ada_b,
                                             float* __restrict__ mod) {
  __shared__ __align__(16) float semb[32][1028];  // silu(emb) f32, padded row (+4)
  const int t = threadIdx.x;
  for (int i = t; i < 8192; i += 512) {           // 8192 float4 = 32x1024
    f32x4 v = ((const f32x4*)emb)[i];
    f32x4 s;
#pragma unroll
    for (int j = 0; j < 4; ++j) s[j] = v[j] / (1.f + __expf(-v[j]));
    *(f32x4*)&semb[i >> 8][(i & 255) << 2] = s;
  }
  __syncthreads();
  const int jl = t >> 5, b = t & 31;
  const int j = blockIdx.x * 16 + jl;
  const f32x4* aw = (const f32x4*)(ada_w + (size_t)j * 1024);
  float acc = 0.f;
  for (int q = 0; q < 256; ++q) {
    f32x4 a = aw[q];
    f32x4 sv = *(const f32x4*)&semb[b][q * 4];
    acc += a[0] * sv[0] + a[1] * sv[1] + a[2] * sv[2] + a[3] * sv[3];
  }
  mod[b * 512 + j] = acc + ada_b[j];
}

// ---------------------------------------------------------------------------
// K2: W'[b][o][c] = conv_w[o][c]*(1+scale[b][c])  (bf16)
//     d[b][o]     = sum_c conv_w[o][c]*shift[b][c] + conv_b[o]
// grid(64,32), 256 threads: wave w -> o = bx*4+w, lane -> 4 c's.
// ---------------------------------------------------------------------------
__global__ __launch_bounds__(256) void k_prep(const float* __restrict__ mod,
                                              const float* __restrict__ conv_w,
                                              const float* __restrict__ conv_b,
                                              unsigned short* __restrict__ wp,
                                              float* __restrict__ dvec) {
  const int b = blockIdx.y;
  const int o = blockIdx.x * 4 + (threadIdx.x >> 6);
  const int l = threadIdx.x & 63;
  const float* sh = mod + b * 512;        // shift = first half
  const float* sc = mod + b * 512 + 256;  // scale = second half
  f32x4 cw = ((const f32x4*)(conv_w + (size_t)o * 256))[l];
  f32x4 s4 = ((const f32x4*)sc)[l];
  f32x4 h4 = ((const f32x4*)sh)[l];
  u16x4 wq;
#pragma unroll
  for (int j = 0; j < 4; ++j) wq[j] = f2bf(cw[j] * (1.f + s4[j]));
  *(u16x4*)(wp + (size_t)b * 65536 + o * 256 + 4 * l) = wq;
  float dd = cw[0] * h4[0] + cw[1] * h4[1] + cw[2] * h4[2] + cw[3] * h4[3];
#pragma unroll
  for (int off = 32; off; off >>= 1) dd += __shfl_down(dd, off);
  if (l == 0) dvec[b * 256 + o] = dd + conv_b[o];
}

// ---------------------------------------------------------------------------
// K3: fused rms + GEMM + selu.  grid(64,32): block = (64-wide s-tile, batch b).
// 512 threads = 8 waves (4 o-rows x 2 s-cols). Tile 256(o) x 64(s), K=256, BK=32.
// A (W') double-buffered via global_load_lds; B (x bf16) in XOR-swizzled LDS:
//   elem(s,c) at lds_bt[s*256 + (c ^ (((s>>1)&7)<<3))]
//   -> b128 frag reads conflict-free (8 lanes/16B slot = throughput floor).
// No inline asm anywhere: compiler owns all waitcnts.
// ---------------------------------------------------------------------------
__device__ __forceinline__ void stage_a(const unsigned short* __restrict__ Wb, int k0,
                                        unsigned char* as_buf, int w, int lane) {
#pragma unroll
  for (int i = 0; i < 2; ++i) {
    int row = (w * 2 + i) * 16 + (lane >> 2);
    const unsigned short* gp = Wb + row * 256 + k0 + (lane & 3) * 8;
    void* lp = as_buf + (w * 2 + i) * 1024;  // wave-uniform LDS base; HW adds lane*16
    __builtin_amdgcn_global_load_lds((const __attribute__((address_space(1))) void*)gp,
                                     (__attribute__((address_space(3))) void*)lp, 16, 0, 0);
  }
}

__global__ __launch_bounds__(512, 4) void k_main(const float* __restrict__ x,
                                                 const unsigned short* __restrict__ wp,
                                                 const float* __restrict__ dvec,
                                                 float* __restrict__ out) {
  constexpr int HW = 4096;
  __shared__ __align__(16) unsigned char lds_as[2 * 16384];   // A dbuf: [2][256 rows][32k]
  __shared__ __align__(16) unsigned short lds_bt[64 * 256];   // B swizzled [s][c^swz]
  __shared__ float lds_part[32 * 64];
  __shared__ float lds_rms[64];
  __shared__ float lds_d[256];

  const int t = threadIdx.x;
  const int b = blockIdx.y;
  const int s0 = blockIdx.x * 64;
  const int w = t >> 6, lane = t & 63;
  const int wr = w >> 1, wc = w & 1;      // wave grid 4(M) x 2(N), each 64x32
  const int lr = lane & 15, g = lane >> 4;

  const unsigned short* Wb = wp + (size_t)b * 65536;

  stage_a(Wb, 0, lds_as, w, lane);        // prefetch A k-step 0
  if (t < 256) lds_d[t] = dvec[b * 256 + t];

  // ---- phase 0: load x tile, sumsq, swizzled-transpose bf16 into lds_bt ----
  const float* xb = x + (size_t)b * (256 * HW) + s0;
  const int sq = t & 15, cg = t >> 4;     // sq: 4-col group, cg: c group 0..31
  f32x4 sacc = {0.f, 0.f, 0.f, 0.f};
#pragma unroll
  for (int it = 0; it < 8; ++it) {
    int c = cg + 32 * it;
    f32x4 v = *(const f32x4*)(xb + (size_t)c * HW + 4 * sq);
    sacc += v * v;
#pragma unroll
    for (int r = 0; r < 4; ++r) {
      int s = 4 * sq + r;
      lds_bt[s * 256 + (c ^ (((s >> 1) & 7) << 3))] = f2bf(v[r]);
    }
  }
  *(f32x4*)(lds_part + cg * 64 + 4 * sq) = sacc;
  __syncthreads();
  if (t < 64) {
    float sum = 0.f;
#pragma unroll 8
    for (int q = 0; q < 32; ++q) sum += lds_part[q * 64 + t];
    lds_rms[t] = rsqrtf(sum * (1.0f / 256.0f) + 1e-6f);
  }

  // ---- GEMM main loop ----
  f32x4 acc[4][2] = {};
  const int sA = 32 * wc + lr;            // n=0 column
  const int sB = sA + 16;                 // n=1 column

  for (int kk = 0; kk < 8; ++kk) {
    const int cur = kk & 1;
    __syncthreads();                      // drains vmcnt: A k-step kk staged; Bs ready
    if (kk < 7) stage_a(Wb, (kk + 1) * 32, lds_as + (cur ^ 1) * 16384, w, lane);

    s16x8 af[4];
#pragma unroll
    for (int m = 0; m < 4; ++m)
      af[m] = *(const s16x8*)(lds_as + cur * 16384 + (64 * wr + 16 * m + lr) * 64 + g * 16);

    const int c0 = kk * 32 + g * 8;
    s16x8 b0 = *(const s16x8*)&lds_bt[sA * 256 + (c0 ^ (((sA >> 1) & 7) << 3))];
    s16x8 b1 = *(const s16x8*)&lds_bt[sB * 256 + (c0 ^ (((sB >> 1) & 7) << 3))];

#pragma unroll
    for (int m = 0; m < 4; ++m) {
      acc[m][0] = __builtin_amdgcn_mfma_f32_16x16x32_bf16(af[m], b0, acc[m][0], 0, 0, 0);
      acc[m][1] = __builtin_amdgcn_mfma_f32_16x16x32_bf16(af[m], b1, acc[m][1], 0, 0, 0);
    }
  }

  // ---- epilogue: y = rms*G + d; selu ----
  float* ob = out + (size_t)b * (256 * HW) + s0;
#pragma unroll
  for (int m = 0; m < 4; ++m) {
    const int o0 = 64 * wr + 16 * m + 4 * g;
#pragma unroll
    for (int n = 0; n < 2; ++n) {
      const int s = 32 * wc + 16 * n + lr;
      const float rr = lds_rms[s];
#pragma unroll
      for (int r = 0; r < 4; ++r) {
        float v = rr * acc[m][n][r] + lds_d[o0 + r];
        float res = v > 0.f ? 1.0507009873554805f * v
                            : 1.7580993408473766f * expm1f(v);
        ob[(size_t)(o0 + r) * HW + s] = res;
      }
    }
  }
}

// ---------------------------------------------------------------------------
extern "C" void kernel_launch(void* const* d_in, const int* in_sizes, int n_in,
                              void* d_out, int out_size, void* d_ws, size_t ws_size,
                              hipStream_t stream) {
  const float* x      = (const float*)d_in[0];
  const float* emb    = (const float*)d_in[1];
  const float* ada_w  = (const float*)d_in[2];
  const float* ada_b  = (const float*)d_in[3];
  const float* conv_w = (const float*)d_in[4];
  const float* conv_b = (const float*)d_in[5];
  float* out = (float*)d_out;

  float* mod  = (float*)d_ws;                               // 32*512 f32
  float* dvec = mod + 32 * 512;                             // 32*256 f32
  unsigned short* wp = (unsigned short*)(dvec + 32 * 256);  // 32*256*256 bf16

  k_mod<<<dim3(32), 512, 0, stream>>>(emb, ada_w, ada_b, mod);
  k_prep<<<dim3(64, 32), 256, 0, stream>>>(mod, conv_w, conv_b, wp, dvec);
  k_main<<<dim3(64, 32), 512, 0, stream>>>(x, wp, dvec, out);
}

// Round 3
// 101.038 us; speedup vs baseline: 1.0120x; 1.0120x over previous
//
#include <hip/hip_runtime.h>
#include <hip/hip_bf16.h>

typedef __attribute__((ext_vector_type(4))) float f32x4;
typedef __attribute__((ext_vector_type(8))) short s16x8;
typedef __attribute__((ext_vector_type(4))) unsigned short u16x4;

__device__ __forceinline__ unsigned short f2bf(float f) {
  unsigned u = __builtin_bit_cast(unsigned, f);
  u += 0x7fffu + ((u >> 16) & 1u);
  return (unsigned short)(u >> 16);
}

// ---------------------------------------------------------------------------
// K1: mod[b][j] = silu(emb[b]) . ada_w[j] + ada_b[j]     (32 x 512), pure f32.
// ---------------------------------------------------------------------------
__global__ __launch_bounds__(512) void k_mod(const float* __restrict__ emb,
                                             const float* __restrict__ ada_w,
                                             const float* __restrict__ ada_b,
                                             float* __restrict__ mod) {
  __shared__ __align__(16) float semb[32][1028];  // silu(emb) f32, padded row (+4)
  const int t = threadIdx.x;
  for (int i = t; i < 8192; i += 512) {           // 8192 float4 = 32x1024
    f32x4 v = ((const f32x4*)emb)[i];
    f32x4 s;
#pragma unroll
    for (int j = 0; j < 4; ++j) s[j] = v[j] / (1.f + __expf(-v[j]));
    *(f32x4*)&semb[i >> 8][(i & 255) << 2] = s;
  }
  __syncthreads();
  const int jl = t >> 5, b = t & 31;
  const int j = blockIdx.x * 16 + jl;
  const f32x4* aw = (const f32x4*)(ada_w + (size_t)j * 1024);
  float acc = 0.f;
  for (int q = 0; q < 256; ++q) {
    f32x4 a = aw[q];
    f32x4 sv = *(const f32x4*)&semb[b][q * 4];
    acc += a[0] * sv[0] + a[1] * sv[1] + a[2] * sv[2] + a[3] * sv[3];
  }
  mod[b * 512 + j] = acc + ada_b[j];
}

// ---------------------------------------------------------------------------
// K2: W'[b][o][c] = conv_w[o][c]*(1+scale[b][c]) (bf16) written in MFMA-frag
// staged layout: chunk id ((o>>6)*4 + ((o>>4)&3))*8 + (c>>5), 512 elem/chunk,
// in-chunk elem = ((c>>3)&3)*128 + (o&15)*8 + (c&7).
// -> k_main A-frag load = one coalesced 1KB dwordx4 per wave.
// Also d[b][o] = sum_c conv_w[o][c]*shift[b][c] + conv_b[o].
// grid(64,32), 256 threads: wave w -> o = bx*4+w, lane l -> c = 4l..4l+3.
// ---------------------------------------------------------------------------
__global__ __launch_bounds__(256) void k_prep(const float* __restrict__ mod,
                                              const float* __restrict__ conv_w,
                                              const float* __restrict__ conv_b,
                                              unsigned short* __restrict__ wp,
                                              float* __restrict__ dvec) {
  const int b = blockIdx.y;
  const int o = blockIdx.x * 4 + (threadIdx.x >> 6);
  const int l = threadIdx.x & 63;
  const float* sh = mod + b * 512;        // shift = first half
  const float* sc = mod + b * 512 + 256;  // scale = second half
  f32x4 cw = ((const f32x4*)(conv_w + (size_t)o * 256))[l];
  f32x4 s4 = ((const f32x4*)sc)[l];
  f32x4 h4 = ((const f32x4*)sh)[l];
  u16x4 wq;
#pragma unroll
  for (int j = 0; j < 4; ++j) wq[j] = f2bf(cw[j] * (1.f + s4[j]));
  const int wr = o >> 6, m = (o >> 4) & 3, lr = o & 15;
  const int kk = l >> 3, g = (l >> 1) & 3, jb = 4 * (l & 1);
  *(u16x4*)(wp + (size_t)b * 65536 + (((wr * 4 + m) * 8 + kk) * 512 + g * 128 + lr * 8 + jb)) = wq;
  float dd = cw[0] * h4[0] + cw[1] * h4[1] + cw[2] * h4[2] + cw[3] * h4[3];
#pragma unroll
  for (int off = 32; off; off >>= 1) dd += __shfl_down(dd, off);
  if (l == 0) dvec[b * 256 + o] = dd + conv_b[o];
}

// ---------------------------------------------------------------------------
// K3: fused rms + GEMM + selu.  grid(64,32): block = (64-wide s-tile, batch b).
// 512 threads = 8 waves (4 o-rows x 2 s-cols); tile 256(o) x 64(s), K=256.
// A read L2->VGPR per K-step (staged layout, coalesced, no LDS, NO barriers
// in the K-loop); B (x bf16) in XOR-swizzled LDS (elem(s,c) at
// lds_bt[s*256 + (c ^ (((s>>1)&7)<<3))]). Only 2 __syncthreads total.
// ---------------------------------------------------------------------------
__global__ __launch_bounds__(512, 4) void k_main(const float* __restrict__ x,
                                                 const unsigned short* __restrict__ wp,
                                                 const float* __restrict__ dvec,
                                                 float* __restrict__ out) {
  constexpr int HW = 4096;
  __shared__ __align__(16) unsigned short lds_bt[64 * 256];  // B swizzled [s][c^swz]
  __shared__ float lds_part[8][64];
  __shared__ float lds_rms[64];
  __shared__ float lds_d[256];

  const int t = threadIdx.x;
  const int b = blockIdx.y;
  const int s0 = blockIdx.x * 64;
  const int w = t >> 6, lane = t & 63;
  const int wr = w >> 1, wc = w & 1;      // wave grid 4(M) x 2(N), each 64x32
  const int lr = lane & 15, g = lane >> 4;

  const unsigned short* A2 = wp + (size_t)b * 65536;

  if (t < 256) lds_d[t] = dvec[b * 256 + t];

  // ---- phase 0: load x tile, sumsq, swizzled-transpose bf16 into lds_bt ----
  const float* xb = x + (size_t)b * (256 * HW) + s0;
  const int sq = t & 15, cg = t >> 4;     // sq: 4-col group, cg: c group 0..31
  f32x4 sacc = {0.f, 0.f, 0.f, 0.f};
#pragma unroll
  for (int it = 0; it < 8; ++it) {
    int c = cg + 32 * it;
    f32x4 v = *(const f32x4*)(xb + (size_t)c * HW + 4 * sq);
    sacc += v * v;
#pragma unroll
    for (int r = 0; r < 4; ++r) {
      int s = 4 * sq + r;
      lds_bt[s * 256 + (c ^ (((s >> 1) & 7) << 3))] = f2bf(v[r]);
    }
  }
  // wave-local reduce across the 4 cg groups sharing sq (lanes l^16, l^32)
#pragma unroll
  for (int off = 16; off <= 32; off <<= 1) {
#pragma unroll
    for (int j = 0; j < 4; ++j) sacc[j] += __shfl_xor(sacc[j], off);
  }
  if (lane < 16) *(f32x4*)&lds_part[w][4 * sq] = sacc;
  __syncthreads();
  if (t < 64) {
    float sum = 0.f;
#pragma unroll
    for (int q = 0; q < 8; ++q) sum += lds_part[q][t];
    lds_rms[t] = rsqrtf(sum * (1.0f / 256.0f) + 1e-6f);
  }
  __syncthreads();

  // ---- GEMM main loop: barrier-free, A from L2, compiler-pipelined ----
  f32x4 acc[4][2] = {};
  const int sA = 32 * wc + lr;            // n=0 column
  const int sB = sA + 16;                 // n=1 column

#pragma unroll
  for (int kk = 0; kk < 8; ++kk) {
    s16x8 af[4];
#pragma unroll
    for (int m = 0; m < 4; ++m)
      af[m] = *(const s16x8*)(A2 + (((wr * 4 + m) * 8 + kk) * 512 + lane * 8));

    const int c0 = kk * 32 + g * 8;
    s16x8 b0 = *(const s16x8*)&lds_bt[sA * 256 + (c0 ^ (((sA >> 1) & 7) << 3))];
    s16x8 b1 = *(const s16x8*)&lds_bt[sB * 256 + (c0 ^ (((sB >> 1) & 7) << 3))];

#pragma unroll
    for (int m = 0; m < 4; ++m) {
      acc[m][0] = __builtin_amdgcn_mfma_f32_16x16x32_bf16(af[m], b0, acc[m][0], 0, 0, 0);
      acc[m][1] = __builtin_amdgcn_mfma_f32_16x16x32_bf16(af[m], b1, acc[m][1], 0, 0, 0);
    }
  }

  // ---- epilogue: y = rms*G + d; selu ----
  float* ob = out + (size_t)b * (256 * HW) + s0;
#pragma unroll
  for (int m = 0; m < 4; ++m) {
    const int o0 = 64 * wr + 16 * m + 4 * g;
#pragma unroll
    for (int n = 0; n < 2; ++n) {
      const int s = 32 * wc + 16 * n + lr;
      const float rr = lds_rms[s];
#pragma unroll
      for (int r = 0; r < 4; ++r) {
        float v = rr * acc[m][n][r] + lds_d[o0 + r];
        float res = v > 0.f ? 1.0507009873554805f * v
                            : 1.7580993408473766f * expm1f(v);
        ob[(size_t)(o0 + r) * HW + s] = res;
      }
    }
  }
}

// ---------------------------------------------------------------------------
extern "C" void kernel_launch(void* const* d_in, const int* in_sizes, int n_in,
                              void* d_out, int out_size, void* d_ws, size_t ws_size,
                              hipStream_t stream) {
  const float* x      = (const float*)d_in[0];
  const float* emb    = (const float*)d_in[1];
  const float* ada_w  = (const float*)d_in[2];
  const float* ada_b  = (const float*)d_in[3];
  const float* conv_w = (const float*)d_in[4];
  const float* conv_b = (const float*)d_in[5];
  float* out = (float*)d_out;

  float* mod  = (float*)d_ws;                               // 32*512 f32
  float* dvec = mod + 32 * 512;                             // 32*256 f32
  unsigned short* wp = (unsigned short*)(dvec + 32 * 256);  // 32*256*256 bf16 (staged layout)

  k_mod<<<dim3(32), 512, 0, stream>>>(emb, ada_w, ada_b, mod);
  k_prep<<<dim3(64, 32), 256, 0, stream>>>(mod, conv_w, conv_b, wp, dvec);
  k_main<<<dim3(64, 32), 512, 0, stream>>>(x, wp, dvec, out);
}

// Round 4
// 96.823 us; speedup vs baseline: 1.0561x; 1.0435x over previous
//
#include <hip/hip_runtime.h>
#include <hip/hip_bf16.h>

typedef __attribute__((ext_vector_type(4))) float f32x4;
typedef __attribute__((ext_vector_type(8))) short s16x8;
typedef __attribute__((ext_vector_type(4))) unsigned short u16x4;

__device__ __forceinline__ unsigned short f2bf(float f) {
  unsigned u = __builtin_bit_cast(unsigned, f);
  u += 0x7fffu + ((u >> 16) & 1u);
  return (unsigned short)(u >> 16);
}

// ---------------------------------------------------------------------------
// K1: mod[b][j] = silu(emb[b]) . ada_w[j] + ada_b[j]     (32 x 512), pure f32.
// ---------------------------------------------------------------------------
__global__ __launch_bounds__(512) void k_mod(const float* __restrict__ emb,
                                             const float* __restrict__ ada_w,
                                             const float* __restrict__ ada_b,
                                             float* __restrict__ mod) {
  __shared__ __align__(16) float semb[32][1028];  // silu(emb) f32, padded row (+4)
  const int t = threadIdx.x;
  for (int i = t; i < 8192; i += 512) {           // 8192 float4 = 32x1024
    f32x4 v = ((const f32x4*)emb)[i];
    f32x4 s;
#pragma unroll
    for (int j = 0; j < 4; ++j) s[j] = v[j] / (1.f + __expf(-v[j]));
    *(f32x4*)&semb[i >> 8][(i & 255) << 2] = s;
  }
  __syncthreads();
  const int jl = t >> 5, b = t & 31;
  const int j = blockIdx.x * 16 + jl;
  const f32x4* aw = (const f32x4*)(ada_w + (size_t)j * 1024);
  float acc = 0.f;
  for (int q = 0; q < 256; ++q) {
    f32x4 a = aw[q];
    f32x4 sv = *(const f32x4*)&semb[b][q * 4];
    acc += a[0] * sv[0] + a[1] * sv[1] + a[2] * sv[2] + a[3] * sv[3];
  }
  mod[b * 512 + j] = acc + ada_b[j];
}

// ---------------------------------------------------------------------------
// K2: W'[b][o][c] = conv_w[o][c]*(1+scale[b][c]) (bf16) written in MFMA-frag
// staged layout: chunk id ((o>>6)*4 + ((o>>4)&3))*8 + (c>>5), 512 elem/chunk,
// in-chunk elem = ((c>>3)&3)*128 + (o&15)*8 + (c&7).
// Also d[b][o] = sum_c conv_w[o][c]*shift[b][c] + conv_b[o].
// ---------------------------------------------------------------------------
__global__ __launch_bounds__(256) void k_prep(const float* __restrict__ mod,
                                              const float* __restrict__ conv_w,
                                              const float* __restrict__ conv_b,
                                              unsigned short* __restrict__ wp,
                                              float* __restrict__ dvec) {
  const int b = blockIdx.y;
  const int o = blockIdx.x * 4 + (threadIdx.x >> 6);
  const int l = threadIdx.x & 63;
  const float* sh = mod + b * 512;        // shift = first half
  const float* sc = mod + b * 512 + 256;  // scale = second half
  f32x4 cw = ((const f32x4*)(conv_w + (size_t)o * 256))[l];
  f32x4 s4 = ((const f32x4*)sc)[l];
  f32x4 h4 = ((const f32x4*)sh)[l];
  u16x4 wq;
#pragma unroll
  for (int j = 0; j < 4; ++j) wq[j] = f2bf(cw[j] * (1.f + s4[j]));
  const int wr = o >> 6, m = (o >> 4) & 3, lr = o & 15;
  const int kk = l >> 3, g = (l >> 1) & 3, jb = 4 * (l & 1);
  *(u16x4*)(wp + (size_t)b * 65536 + (((wr * 4 + m) * 8 + kk) * 512 + g * 128 + lr * 8 + jb)) = wq;
  float dd = cw[0] * h4[0] + cw[1] * h4[1] + cw[2] * h4[2] + cw[3] * h4[3];
#pragma unroll
  for (int off = 32; off; off >>= 1) dd += __shfl_down(dd, off);
  if (l == 0) dvec[b * 256 + o] = dd + conv_b[o];
}

// ---------------------------------------------------------------------------
// K3: fused rms + GEMM + selu.  grid(64,32): block = (64-wide s-tile, batch b).
// 512 threads = 8 waves (4 o-rows x 2 s-cols); tile 256(o) x 64(s), K=256.
// A L2->VGPR with explicit 2-deep prefetch; B via XOR-swizzled LDS transpose.
// rms applied only in the epilogue -> its barrier sits AFTER the K-loop.
// ---------------------------------------------------------------------------
__global__ __launch_bounds__(512, 2) void k_main(const float* __restrict__ x,
                                                 const unsigned short* __restrict__ wp,
                                                 const float* __restrict__ dvec,
                                                 float* __restrict__ out) {
  constexpr int HW = 4096;
  __shared__ __align__(16) unsigned short lds_bt[64 * 256];  // B swizzled [s][c^swz]
  __shared__ float lds_part[8][64];
  __shared__ float lds_rms[64];
  __shared__ float lds_d[256];

  const int t = threadIdx.x;
  const int b = blockIdx.y;
  const int s0 = blockIdx.x * 64;
  const int w = t >> 6, lane = t & 63;
  const int wr = w >> 1, wc = w & 1;      // wave grid 4(M) x 2(N), each 64x32
  const int lr = lane & 15, g = lane >> 4;

  const unsigned short* A2 = wp + (size_t)b * 65536;

  if (t < 256) lds_d[t] = dvec[b * 256 + t];

  // ---- phase 0: load x tile, sumsq, swizzled-transpose bf16 into lds_bt ----
  const float* xb = x + (size_t)b * (256 * HW) + s0;
  const int sq = t & 15, cg = t >> 4;     // sq: 4-col group, cg: c group 0..31
  f32x4 sacc = {0.f, 0.f, 0.f, 0.f};
#pragma unroll
  for (int it = 0; it < 8; ++it) {
    int c = cg + 32 * it;
    f32x4 v = *(const f32x4*)(xb + (size_t)c * HW + 4 * sq);
    sacc += v * v;
#pragma unroll
    for (int r = 0; r < 4; ++r) {
      int s = 4 * sq + r;
      lds_bt[s * 256 + (c ^ (((s >> 1) & 7) << 3))] = f2bf(v[r]);
    }
  }
#pragma unroll
  for (int off = 16; off <= 32; off <<= 1) {
#pragma unroll
    for (int j = 0; j < 4; ++j) sacc[j] += __shfl_xor(sacc[j], off);
  }
  if (lane < 16) *(f32x4*)&lds_part[w][4 * sq] = sacc;
  __syncthreads();                        // lds_bt + lds_part ready
  if (t < 64) {                           // wave 0 computes rms; others go to GEMM
    float sum = 0.f;
#pragma unroll
    for (int q = 0; q < 8; ++q) sum += lds_part[q][t];
    lds_rms[t] = rsqrtf(sum * (1.0f / 256.0f) + 1e-6f);
  }

  // ---- GEMM main loop: barrier-free, explicit 2-deep pipeline ----
  f32x4 acc[4][2] = {};
  const int sA = 32 * wc + lr;            // n=0 column
  const int sB = sA + 16;                 // n=1 column
  const unsigned swA = ((sA >> 1) & 7) << 3;
  const unsigned swB = ((sB >> 1) & 7) << 3;

  s16x8 afc[4], afn[4], b0c, b1c, b0n, b1n;
#pragma unroll
  for (int m = 0; m < 4; ++m)
    afc[m] = *(const s16x8*)(A2 + (((wr * 4 + m) * 8 + 0) * 512 + lane * 8));
  {
    const int c0 = 0 * 32 + g * 8;
    b0c = *(const s16x8*)&lds_bt[sA * 256 + (c0 ^ swA)];
    b1c = *(const s16x8*)&lds_bt[sB * 256 + (c0 ^ swB)];
  }

#pragma unroll
  for (int kk = 0; kk < 8; ++kk) {
    if (kk < 7) {
#pragma unroll
      for (int m = 0; m < 4; ++m)
        afn[m] = *(const s16x8*)(A2 + (((wr * 4 + m) * 8 + kk + 1) * 512 + lane * 8));
      const int c1 = (kk + 1) * 32 + g * 8;
      b0n = *(const s16x8*)&lds_bt[sA * 256 + (c1 ^ swA)];
      b1n = *(const s16x8*)&lds_bt[sB * 256 + (c1 ^ swB)];
    }
#pragma unroll
    for (int m = 0; m < 4; ++m) {
      acc[m][0] = __builtin_amdgcn_mfma_f32_16x16x32_bf16(afc[m], b0c, acc[m][0], 0, 0, 0);
      acc[m][1] = __builtin_amdgcn_mfma_f32_16x16x32_bf16(afc[m], b1c, acc[m][1], 0, 0, 0);
    }
#pragma unroll
    for (int m = 0; m < 4; ++m) afc[m] = afn[m];
    b0c = b0n;
    b1c = b1n;
  }

  __syncthreads();                        // lds_rms ready

  // ---- epilogue: y = rms*G + d; selu via v_exp ----
  float* ob = out + (size_t)b * (256 * HW) + s0;
#pragma unroll
  for (int m = 0; m < 4; ++m) {
    const int o0 = 64 * wr + 16 * m + 4 * g;
    const f32x4 dv = *(const f32x4*)&lds_d[o0];
#pragma unroll
    for (int n = 0; n < 2; ++n) {
      const int s = 32 * wc + 16 * n + lr;
      const float rr = lds_rms[s];
#pragma unroll
      for (int r = 0; r < 4; ++r) {
        float v = rr * acc[m][n][r] + dv[r];
        float res = v > 0.f ? 1.0507009873554805f * v
                            : 1.7580993408473766f * (__expf(v) - 1.f);
        ob[(size_t)(o0 + r) * HW + s] = res;
      }
    }
  }
}

// ---------------------------------------------------------------------------
extern "C" void kernel_launch(void* const* d_in, const int* in_sizes, int n_in,
                              void* d_out, int out_size, void* d_ws, size_t ws_size,
                              hipStream_t stream) {
  const float* x      = (const float*)d_in[0];
  const float* emb    = (const float*)d_in[1];
  const float* ada_w  = (const float*)d_in[2];
  const float* ada_b  = (const float*)d_in[3];
  const float* conv_w = (const float*)d_in[4];
  const float* conv_b = (const float*)d_in[5];
  float* out = (float*)d_out;

  float* mod  = (float*)d_ws;                               // 32*512 f32
  float* dvec = mod + 32 * 512;                             // 32*256 f32
  unsigned short* wp = (unsigned short*)(dvec + 32 * 256);  // 32*256*256 bf16 (staged layout)

  k_mod<<<dim3(32), 512, 0, stream>>>(emb, ada_w, ada_b, mod);
  k_prep<<<dim3(64, 32), 256, 0, stream>>>(mod, conv_w, conv_b, wp, dvec);
  k_main<<<dim3(64, 32), 512, 0, stream>>>(x, wp, dvec, out);
}